// Round 12
// baseline (99.514 us; speedup 1.0000x reference)
//
#include <hip/hip_runtime.h>
#include <hip/hip_bf16.h>
#include <stdint.h>

#define S_LEN 2048
#define D_DIM 64
#define BH    64
#define NQT   8           // q-tiles of 256 rows
#define LOG2E 1.44269504088896f
#define THR   8.0f
#define TEN_ELEMS (BH * S_LEN * D_DIM)

typedef __attribute__((ext_vector_type(8)))  short bf16x8;
typedef __attribute__((ext_vector_type(4)))  short s16x4;
typedef __attribute__((ext_vector_type(4)))  float f32x4;
typedef __attribute__((ext_vector_type(16))) float f32x16;
typedef __attribute__((ext_vector_type(4)))  uint32_t u32x4;

__device__ __forceinline__ short f2bf(float f) {
    uint32_t u = __builtin_bit_cast(uint32_t, f);
    u += 0x7FFFu + ((u >> 16) & 1u);   // RNE
    return (short)(u >> 16);
}

// packed f32->bf16 (emits v_cvt_pk_bf16_f32); memcpy because __hip_bfloat162
// is not trivially copyable.
__device__ __forceinline__ uint32_t pkbf(float lo, float hi) {
    __hip_bfloat162 h = __float22bfloat162_rn(make_float2(lo, hi));
    uint32_t r;
    __builtin_memcpy(&r, &h, 4);
    return r;
}

// cross-half (lane ^ 32) exchange helpers — unambiguous semantics.
__device__ __forceinline__ float xhalf_max(float v) {
    return fmaxf(v, __shfl_xor(v, 32));
}
__device__ __forceinline__ float xhalf_sum(float v) {
    return v + __shfl_xor(v, 32);
}

// XOR swizzle on short-index of a [rows][64]-short LDS tile (byte bits 4..6).
__device__ __forceinline__ int swz(int row, int col) {
    return (row * 64 + col) ^ ((row & 7) << 3);
}

#if __has_builtin(__builtin_amdgcn_exp2f)
#define EXP2(x) __builtin_amdgcn_exp2f(x)
#else
#define EXP2(x) exp2f(x)
#endif

// ============================ pre-pass kernels ============================
__global__ __launch_bounds__(256)
void cvt_qk_kernel(const float* __restrict__ Q, const float* __restrict__ K,
                   short* __restrict__ Qb, short* __restrict__ Kb)
{
    const size_t off = ((size_t)blockIdx.x * 256 + threadIdx.x) * 8;
    const float sc = 0.125f * LOG2E;
    f32x4 a0 = *(const f32x4*)(Q + off), a1 = *(const f32x4*)(Q + off + 4);
    f32x4 b0 = *(const f32x4*)(K + off), b1 = *(const f32x4*)(K + off + 4);
    bf16x8 qa, kb;
    #pragma unroll
    for (int j = 0; j < 4; ++j) {
        qa[j] = f2bf(a0[j] * sc); qa[4 + j] = f2bf(a1[j] * sc);
        kb[j] = f2bf(b0[j]);      kb[4 + j] = f2bf(b1[j]);
    }
    *(bf16x8*)(Qb + off) = qa;
    *(bf16x8*)(Kb + off) = kb;
}

// V^T pre-pass with kv quad-permute (quad 1 <-> 2 within each 16-row group):
// stored kv order matches the MFMA D->A slot order, so the PV A-fragment is
// a straight pack of each lane's own P values — no cross-lane exchange.
__global__ __launch_bounds__(256)
void vt_kernel(const float* __restrict__ V, short* __restrict__ Vt)
{
    const int kt = blockIdx.x;              // kv tile 0..31
    const int bh = blockIdx.y;
    const float* Vp = V + (size_t)bh * S_LEN * D_DIM + (size_t)kt * 64 * D_DIM;
    short* Vo = Vt + (size_t)bh * D_DIM * S_LEN;
    __shared__ short T[64][72];             // +8 pad
    const int tid = threadIdx.x;
    const int row = tid >> 2, q4 = tid & 3;
    #pragma unroll
    for (int j = 0; j < 4; ++j) {
        f32x4 v = *(const f32x4*)(Vp + row * D_DIM + q4 * 16 + j * 4);
        #pragma unroll
        for (int e = 0; e < 4; ++e) T[row][q4 * 16 + j * 4 + e] = f2bf(v[e]);
    }
    __syncthreads();
    const int d = tid >> 2, kq = tid & 3;
    #pragma unroll
    for (int j = 0; j < 4; ++j) {
        s16x4 w;
        #pragma unroll
        for (int e = 0; e < 4; ++e) w[e] = T[kq * 16 + j * 4 + e][d];
        const int jd = (j == 1) ? 2 : ((j == 2) ? 1 : j);   // quad 1 <-> 2
        *(s16x4*)&Vo[(size_t)d * S_LEN + kt * 64 + kq * 16 + jd * 4] = w;
    }
}

// ============================ hot kernel ============================
// 512 threads stage 1024 s16x4 quads per tensor per tile: 2 iters each.
#define ISSUE_B(kb) do { \
    const short* kp_ = Kp + (size_t)(kb) * 64 * D_DIM; \
    const short* vp_ = Vtp + (kb) * 64; \
    _Pragma("unroll") for (int it = 0; it < 2; ++it) { \
        const int idx_ = tid + it * 512; \
        const int row_ = idx_ >> 4, c4_ = idx_ & 15; \
        kreg[it] = *(const s16x4*)(kp_ + row_ * D_DIM + c4_ * 4); \
        vreg[it] = *(const s16x4*)(vp_ + (size_t)row_ * S_LEN + c4_ * 4); \
    } \
} while (0)

#define WRITE_LDS_B(b) do { \
    _Pragma("unroll") for (int it = 0; it < 2; ++it) { \
        const int idx_ = tid + it * 512; \
        const int row_ = idx_ >> 4, c4_ = idx_ & 15; \
        *(s16x4*)&Kl[b][swz(row_, c4_ * 4)] = kreg[it]; \
        *(s16x4*)&Vl[b][swz(row_, c4_ * 4)] = vreg[it]; \
    } \
} while (0)

// PV A-fragment: straight pack of the lane's 8 P-values (V rows were
// pre-permuted by sigma in vt_kernel, so slot order already matches).
#define MKFRAG(dst, sv, R0) do { \
    u32x4 t_; \
    t_[0] = pkbf(sv[(R0)+0], sv[(R0)+1]); \
    t_[1] = pkbf(sv[(R0)+2], sv[(R0)+3]); \
    t_[2] = pkbf(sv[(R0)+4], sv[(R0)+5]); \
    t_[3] = pkbf(sv[(R0)+6], sv[(R0)+7]); \
    dst = __builtin_bit_cast(bf16x8, t_); \
} while (0)

#define PVSTEP(pa, koff, acc0, acc1, b) do { \
    bf16x8 vf0_ = *(const bf16x8*)&Vl[b][swz(lq32,      (koff) + hi * 8)]; \
    bf16x8 vf1_ = *(const bf16x8*)&Vl[b][swz(32 + lq32, (koff) + hi * 8)]; \
    acc0 = __builtin_amdgcn_mfma_f32_32x32x16_bf16(pa, vf0_, acc0, 0, 0, 0); \
    acc1 = __builtin_amdgcn_mfma_f32_32x32x16_bf16(pa, vf1_, acc1, 0, 0, 0); \
} while (0)

// Swapped QK^T with 32x32x16: S^T[kv][q]; lane: q = lq32,
// kv = kvsub*32 + (r&3) + 8*(r>>2) + 4*hi.  Softmax fully in-lane + 1 xhalf.
#define COMPUTE32(qf, acc0, acc1, mm, ll, q0, kv0, b) do { \
    f32x16 s0_ = (f32x16)0.f, s1_ = (f32x16)0.f; \
    __builtin_amdgcn_s_setprio(1); \
    _Pragma("unroll") for (int c = 0; c < 4; ++c) { \
        bf16x8 k0_ = *(const bf16x8*)&Kl[b][swz(lq32,      c * 16 + hi * 8)]; \
        bf16x8 k1_ = *(const bf16x8*)&Kl[b][swz(32 + lq32, c * 16 + hi * 8)]; \
        s0_ = __builtin_amdgcn_mfma_f32_32x32x16_bf16(k0_, qf[c], s0_, 0, 0, 0); \
        s1_ = __builtin_amdgcn_mfma_f32_32x32x16_bf16(k1_, qf[c], s1_, 0, 0, 0); \
    } \
    __builtin_amdgcn_s_setprio(0); \
    if ((kv0) + 63 > (q0)) {   /* diagonal tile: causal mask */ \
        _Pragma("unroll") for (int r = 0; r < 16; ++r) { \
            const int kvr_ = (r & 3) + 8 * (r >> 2) + 4 * hi; \
            if ((kv0) + kvr_      > (q0) + lq32) s0_[r] = -1e30f; \
            if ((kv0) + 32 + kvr_ > (q0) + lq32) s1_[r] = -1e30f; \
        } \
    } \
    float m0_ = fmaxf(s0_[0], s1_[0]), m1_ = fmaxf(s0_[1], s1_[1]); \
    float m2_ = fmaxf(s0_[2], s1_[2]), m3_ = fmaxf(s0_[3], s1_[3]); \
    _Pragma("unroll") for (int r = 4; r < 16; r += 4) { \
        m0_ = fmaxf(m0_, fmaxf(s0_[r],     s1_[r])); \
        m1_ = fmaxf(m1_, fmaxf(s0_[r + 1], s1_[r + 1])); \
        m2_ = fmaxf(m2_, fmaxf(s0_[r + 2], s1_[r + 2])); \
        m3_ = fmaxf(m3_, fmaxf(s0_[r + 3], s1_[r + 3])); \
    } \
    float pmax_ = xhalf_max(fmaxf(fmaxf(m0_, m1_), fmaxf(m2_, m3_))); \
    if (!__all(pmax_ <= (mm) + THR)) {      /* defer-max: rare rescale */ \
        const float mn_ = fmaxf((mm), pmax_); \
        const float f_  = EXP2((mm) - mn_); \
        (ll) *= f_; \
        _Pragma("unroll") for (int r = 0; r < 16; ++r) { \
            const float fr_ = __shfl(f_, (r & 3) + 8 * (r >> 2) + 4 * hi); \
            acc0[r] *= fr_; acc1[r] *= fr_; \
        } \
        (mm) = mn_; \
    } \
    float t0_ = 0.f, t1_ = 0.f, t2_ = 0.f, t3_ = 0.f; \
    _Pragma("unroll") for (int r = 0; r < 16; r += 4) { \
        s0_[r]     = EXP2(s0_[r]     - (mm)); s1_[r]     = EXP2(s1_[r]     - (mm)); \
        s0_[r + 1] = EXP2(s0_[r + 1] - (mm)); s1_[r + 1] = EXP2(s1_[r + 1] - (mm)); \
        s0_[r + 2] = EXP2(s0_[r + 2] - (mm)); s1_[r + 2] = EXP2(s1_[r + 2] - (mm)); \
        s0_[r + 3] = EXP2(s0_[r + 3] - (mm)); s1_[r + 3] = EXP2(s1_[r + 3] - (mm)); \
        t0_ += s0_[r]     + s1_[r]; \
        t1_ += s0_[r + 1] + s1_[r + 1]; \
        t2_ += s0_[r + 2] + s1_[r + 2]; \
        t3_ += s0_[r + 3] + s1_[r + 3]; \
    } \
    (ll) += (t0_ + t1_) + (t2_ + t3_);      /* in-lane half-sum; combine at end */ \
    bf16x8 pa0_, pa1_, pa2_, pa3_; \
    MKFRAG(pa0_, s0_, 0); MKFRAG(pa1_, s0_, 8); \
    MKFRAG(pa2_, s1_, 0); MKFRAG(pa3_, s1_, 8); \
    __builtin_amdgcn_s_setprio(1); \
    PVSTEP(pa0_, 0,  acc0, acc1, b); \
    PVSTEP(pa1_, 16, acc0, acc1, b); \
    PVSTEP(pa2_, 32, acc0, acc1, b); \
    PVSTEP(pa3_, 48, acc0, acc1, b); \
    __builtin_amdgcn_s_setprio(0); \
} while (0)

// 8-wave blocks, 256 q-rows each: 2 blocks/CU x 8 waves = 16 waves/CU
// (2x the R11 residency at identical per-wave VGPR and 32KB LDS).
__global__ __launch_bounds__(512, 2)
void attn_fwd_bf16(const short* __restrict__ Qb, const short* __restrict__ Kb,
                   const short* __restrict__ Vt, float* __restrict__ Out)
{
    const int bh   = blockIdx.x;           // 0..63 (fast dim)
    const int qt   = NQT - 1 - blockIdx.y; // heavy q-tiles dispatch first
    const int tid  = threadIdx.x;
    const int wid  = tid >> 6;             // 0..7
    const int lane = tid & 63;
    const int lq32 = lane & 31;
    const int hi   = lane >> 5;

    const int nkv = 4 * qt + 4;            // 64-wide kv tiles

    const short* Qp  = Qb + (size_t)bh * S_LEN * D_DIM;
    const short* Kp  = Kb + (size_t)bh * S_LEN * D_DIM;
    const short* Vtp = Vt + (size_t)bh * D_DIM * S_LEN;
    float*       Op  = Out + (size_t)bh * S_LEN * D_DIM;

    __shared__ __align__(16) short Kl[2][64 * 64];
    __shared__ __align__(16) short Vl[2][64 * 64];   // V^T tile [d][kv-permuted]

    const int q0 = qt * 256 + wid * 32;

    // Q fragments (B-operand): col q = lq32, k(d) = c*16 + hi*8 + j
    bf16x8 qf[4];
    #pragma unroll
    for (int c = 0; c < 4; ++c)
        qf[c] = *(const bf16x8*)(Qp + (size_t)(q0 + lq32) * D_DIM + c * 16 + hi * 8);

    f32x16 acc0 = (f32x16)0.f, acc1 = (f32x16)0.f;
    float m = -1e30f, l = 0.f;

    s16x4 kreg[2], vreg[2];

    ISSUE_B(0);
    WRITE_LDS_B(0);
    __syncthreads();

    for (int j = 0; j < nkv; ++j) {
        const int  kv0  = j * 64;
        const int  buf  = j & 1;
        const bool more = (j + 1) < nkv;
        if (more) ISSUE_B(j + 1);                     // loads fly under compute
        if (kv0 <= q0 + 31) COMPUTE32(qf, acc0, acc1, m, l, q0, kv0, buf);
        if (more) {                                   // single barrier per tile
            WRITE_LDS_B(buf ^ 1);
            __syncthreads();
        }
    }

    // ---- epilogue: combine half-sums, O = acc / l ----
    l = xhalf_sum(l);
    const float il = 1.f / l;
    #pragma unroll
    for (int r = 0; r < 16; ++r) {
        const int qr   = (r & 3) + 8 * (r >> 2) + 4 * hi;
        const float vl = __shfl(il, qr);
        Op[(size_t)(q0 + qr) * D_DIM + lq32]      = acc0[r] * vl;
        Op[(size_t)(q0 + qr) * D_DIM + 32 + lq32] = acc1[r] * vl;
    }
}

extern "C" void kernel_launch(void* const* d_in, const int* in_sizes, int n_in,
                              void* d_out, int out_size, void* d_ws, size_t ws_size,
                              hipStream_t stream) {
    const float* q = (const float*)d_in[0];
    const float* k = (const float*)d_in[1];
    const float* v = (const float*)d_in[2];
    // d_in[3] (causal tril mask) handled analytically.
    float* out = (float*)d_out;
    (void)in_sizes; (void)n_in; (void)out_size; (void)ws_size;

    // ws: Qb, Kb, Vt bf16 tensors (50.3 MB; harness ws verified >= this in R6)
    short* Qb = (short*)d_ws;
    short* Kb = Qb + TEN_ELEMS;
    short* Vt = Kb + TEN_ELEMS;
    cvt_qk_kernel<<<TEN_ELEMS / 8 / 256, 256, 0, stream>>>(q, k, Qb, Kb);
    vt_kernel<<<dim3(S_LEN / 64, BH), 256, 0, stream>>>(v, Vt);
    attn_fwd_bf16<<<dim3(BH, NQT), 512, 0, stream>>>(Qb, Kb, Vt, out);
}

// Round 13
// 95.831 us; speedup vs baseline: 1.0384x; 1.0384x over previous
//
#include <hip/hip_runtime.h>
#include <hip/hip_bf16.h>
#include <stdint.h>

#define S_LEN 2048
#define D_DIM 64
#define BH    64
#define NQT   16          // q-tiles of 128 rows
#define LOG2E 1.44269504088896f
#define THR   8.0f
#define TEN_ELEMS (BH * S_LEN * D_DIM)

typedef __attribute__((ext_vector_type(8)))  short bf16x8;
typedef __attribute__((ext_vector_type(4)))  short s16x4;
typedef __attribute__((ext_vector_type(4)))  float f32x4;
typedef __attribute__((ext_vector_type(16))) float f32x16;
typedef __attribute__((ext_vector_type(4)))  uint32_t u32x4;

__device__ __forceinline__ short f2bf(float f) {
    uint32_t u = __builtin_bit_cast(uint32_t, f);
    u += 0x7FFFu + ((u >> 16) & 1u);   // RNE
    return (short)(u >> 16);
}

// packed f32->bf16 (emits v_cvt_pk_bf16_f32); memcpy because __hip_bfloat162
// is not trivially copyable.
__device__ __forceinline__ uint32_t pkbf(float lo, float hi) {
    __hip_bfloat162 h = __float22bfloat162_rn(make_float2(lo, hi));
    uint32_t r;
    __builtin_memcpy(&r, &h, 4);
    return r;
}

__device__ __forceinline__ float xhalf_max(float v) {
    return fmaxf(v, __shfl_xor(v, 32));
}
__device__ __forceinline__ float xhalf_sum(float v) {
    return v + __shfl_xor(v, 32);
}

// XOR swizzle on short-index of a [rows][64]-short LDS tile (byte bits 4..6).
__device__ __forceinline__ int swz(int row, int col) {
    return (row * 64 + col) ^ ((row & 7) << 3);
}

#if __has_builtin(__builtin_amdgcn_exp2f)
#define EXP2(x) __builtin_amdgcn_exp2f(x)
#else
#define EXP2(x) exp2f(x)
#endif

// ============================ pre-pass kernels ============================
__global__ __launch_bounds__(256)
void cvt_qk_kernel(const float* __restrict__ Q, const float* __restrict__ K,
                   short* __restrict__ Qb, short* __restrict__ Kb)
{
    const size_t off = ((size_t)blockIdx.x * 256 + threadIdx.x) * 8;
    const float sc = 0.125f * LOG2E;
    f32x4 a0 = *(const f32x4*)(Q + off), a1 = *(const f32x4*)(Q + off + 4);
    f32x4 b0 = *(const f32x4*)(K + off), b1 = *(const f32x4*)(K + off + 4);
    bf16x8 qa, kb;
    #pragma unroll
    for (int j = 0; j < 4; ++j) {
        qa[j] = f2bf(a0[j] * sc); qa[4 + j] = f2bf(a1[j] * sc);
        kb[j] = f2bf(b0[j]);      kb[4 + j] = f2bf(b1[j]);
    }
    *(bf16x8*)(Qb + off) = qa;
    *(bf16x8*)(Kb + off) = kb;
}

// V^T pre-pass with kv quad-permute (quad 1 <-> 2 within each 16-row group):
// stored kv order matches the MFMA D->A slot order, so the PV A-fragment is
// a straight pack of each lane's own P values — no cross-lane exchange.
__global__ __launch_bounds__(256)
void vt_kernel(const float* __restrict__ V, short* __restrict__ Vt)
{
    const int kt = blockIdx.x;              // kv tile 0..31
    const int bh = blockIdx.y;
    const float* Vp = V + (size_t)bh * S_LEN * D_DIM + (size_t)kt * 64 * D_DIM;
    short* Vo = Vt + (size_t)bh * D_DIM * S_LEN;
    __shared__ short T[64][72];             // +8 pad
    const int tid = threadIdx.x;
    const int row = tid >> 2, q4 = tid & 3;
    #pragma unroll
    for (int j = 0; j < 4; ++j) {
        f32x4 v = *(const f32x4*)(Vp + row * D_DIM + q4 * 16 + j * 4);
        #pragma unroll
        for (int e = 0; e < 4; ++e) T[row][q4 * 16 + j * 4 + e] = f2bf(v[e]);
    }
    __syncthreads();
    const int d = tid >> 2, kq = tid & 3;
    #pragma unroll
    for (int j = 0; j < 4; ++j) {
        s16x4 w;
        #pragma unroll
        for (int e = 0; e < 4; ++e) w[e] = T[kq * 16 + j * 4 + e][d];
        const int jd = (j == 1) ? 2 : ((j == 2) ? 1 : j);   // quad 1 <-> 2
        *(s16x4*)&Vo[(size_t)d * S_LEN + kt * 64 + kq * 16 + jd * 4] = w;
    }
}

// ============================ hot kernel ============================
#define ISSUE_B(kb) do { \
    const short* kp_ = Kp + (size_t)(kb) * 64 * D_DIM; \
    const short* vp_ = Vtp + (kb) * 64; \
    _Pragma("unroll") for (int it = 0; it < 4; ++it) { \
        const int idx_ = tid + it * 256; \
        const int row_ = idx_ >> 4, c4_ = idx_ & 15; \
        kreg[it] = *(const s16x4*)(kp_ + row_ * D_DIM + c4_ * 4); \
        vreg[it] = *(const s16x4*)(vp_ + (size_t)row_ * S_LEN + c4_ * 4); \
    } \
} while (0)

// write staged regs into LDS tile slot (pointers Kd_, Vd_)
#define WRITE_LDS_B(Kd_, Vd_) do { \
    _Pragma("unroll") for (int it = 0; it < 4; ++it) { \
        const int idx_ = tid + it * 256; \
        const int row_ = idx_ >> 4, c4_ = idx_ & 15; \
        *(s16x4*)&(Kd_)[swz(row_, c4_ * 4)] = kreg[it]; \
        *(s16x4*)&(Vd_)[swz(row_, c4_ * 4)] = vreg[it]; \
    } \
} while (0)

// PV A-fragment: straight pack of the lane's 8 P-values (V rows pre-permuted).
#define MKFRAG(dst, sv, R0) do { \
    u32x4 t_; \
    t_[0] = pkbf(sv[(R0)+0], sv[(R0)+1]); \
    t_[1] = pkbf(sv[(R0)+2], sv[(R0)+3]); \
    t_[2] = pkbf(sv[(R0)+4], sv[(R0)+5]); \
    t_[3] = pkbf(sv[(R0)+6], sv[(R0)+7]); \
    dst = __builtin_bit_cast(bf16x8, t_); \
} while (0)

#define PVSTEP(pa, koff, Vb_) do { \
    bf16x8 vf0_ = *(const bf16x8*)&(Vb_)[swz(lq32,      (koff) + hi * 8)]; \
    bf16x8 vf1_ = *(const bf16x8*)&(Vb_)[swz(32 + lq32, (koff) + hi * 8)]; \
    acc0 = __builtin_amdgcn_mfma_f32_32x32x16_bf16(pa, vf0_, acc0, 0, 0, 0); \
    acc1 = __builtin_amdgcn_mfma_f32_32x32x16_bf16(pa, vf1_, acc1, 0, 0, 0); \
} while (0)

// QK^T for one 64-kv tile into (sd0, sd1) + causal mask.  Swapped operands:
// S^T[kv][q]; lane: q = lq32, kv = kvsub*32 + (r&3)+8*(r>>2)+4*hi.
#define QK32(sd0, sd1, kv0, Kb_) do { \
    sd0 = (f32x16)0.f; sd1 = (f32x16)0.f; \
    __builtin_amdgcn_s_setprio(1); \
    _Pragma("unroll") for (int c = 0; c < 4; ++c) { \
        bf16x8 k0_ = *(const bf16x8*)&(Kb_)[swz(lq32,      c * 16 + hi * 8)]; \
        bf16x8 k1_ = *(const bf16x8*)&(Kb_)[swz(32 + lq32, c * 16 + hi * 8)]; \
        sd0 = __builtin_amdgcn_mfma_f32_32x32x16_bf16(k0_, qf[c], sd0, 0, 0, 0); \
        sd1 = __builtin_amdgcn_mfma_f32_32x32x16_bf16(k1_, qf[c], sd1, 0, 0, 0); \
    } \
    __builtin_amdgcn_s_setprio(0); \
    if ((kv0) + 63 > q0) { \
        _Pragma("unroll") for (int r = 0; r < 16; ++r) { \
            const int kvr_ = (r & 3) + 8 * (r >> 2) + 4 * hi; \
            if ((kv0) + kvr_      > q0 + lq32) sd0[r] = -1e30f; \
            if ((kv0) + 32 + kvr_ > q0 + lq32) sd1[r] = -1e30f; \
        } \
    } \
} while (0)

// softmax + PV for a tile whose scores sit in (s0_, s1_).
#define SMPV32(s0_, s1_, Vb_) do { \
    float m0_ = fmaxf(s0_[0], s1_[0]), m1_ = fmaxf(s0_[1], s1_[1]); \
    float m2_ = fmaxf(s0_[2], s1_[2]), m3_ = fmaxf(s0_[3], s1_[3]); \
    _Pragma("unroll") for (int r = 4; r < 16; r += 4) { \
        m0_ = fmaxf(m0_, fmaxf(s0_[r],     s1_[r])); \
        m1_ = fmaxf(m1_, fmaxf(s0_[r + 1], s1_[r + 1])); \
        m2_ = fmaxf(m2_, fmaxf(s0_[r + 2], s1_[r + 2])); \
        m3_ = fmaxf(m3_, fmaxf(s0_[r + 3], s1_[r + 3])); \
    } \
    float pmax_ = xhalf_max(fmaxf(fmaxf(m0_, m1_), fmaxf(m2_, m3_))); \
    if (!__all(pmax_ <= m + THR)) {      /* defer-max: rare rescale */ \
        const float mn_ = fmaxf(m, pmax_); \
        const float f_  = EXP2(m - mn_); \
        l *= f_; \
        _Pragma("unroll") for (int r = 0; r < 16; ++r) { \
            const float fr_ = __shfl(f_, (r & 3) + 8 * (r >> 2) + 4 * hi); \
            acc0[r] *= fr_; acc1[r] *= fr_; \
        } \
        m = mn_; \
    } \
    float t0_ = 0.f, t1_ = 0.f, t2_ = 0.f, t3_ = 0.f; \
    _Pragma("unroll") for (int r = 0; r < 16; r += 4) { \
        s0_[r]     = EXP2(s0_[r]     - m); s1_[r]     = EXP2(s1_[r]     - m); \
        s0_[r + 1] = EXP2(s0_[r + 1] - m); s1_[r + 1] = EXP2(s1_[r + 1] - m); \
        s0_[r + 2] = EXP2(s0_[r + 2] - m); s1_[r + 2] = EXP2(s1_[r + 2] - m); \
        s0_[r + 3] = EXP2(s0_[r + 3] - m); s1_[r + 3] = EXP2(s1_[r + 3] - m); \
        t0_ += s0_[r]     + s1_[r]; \
        t1_ += s0_[r + 1] + s1_[r + 1]; \
        t2_ += s0_[r + 2] + s1_[r + 2]; \
        t3_ += s0_[r + 3] + s1_[r + 3]; \
    } \
    l += (t0_ + t1_) + (t2_ + t3_); \
    bf16x8 pa0_, pa1_, pa2_, pa3_; \
    MKFRAG(pa0_, s0_, 0); MKFRAG(pa1_, s0_, 8); \
    MKFRAG(pa2_, s1_, 0); MKFRAG(pa3_, s1_, 8); \
    __builtin_amdgcn_s_setprio(1); \
    PVSTEP(pa0_, 0,  Vb_); \
    PVSTEP(pa1_, 16, Vb_); \
    PVSTEP(pa2_, 32, Vb_); \
    PVSTEP(pa3_, 48, Vb_); \
    __builtin_amdgcn_s_setprio(0); \
} while (0)

// Pipelined: QK(t+1) issues in the same inter-barrier phase as softmax+PV(t)
// (independent -> scheduler interleaves; QK MFMA hides under softmax VALU).
// Triple-buffered LDS so tile t+1's K is staged before softmax(t) starts;
// every buffer-reuse pair (tile x vs x+3) is separated by >=1 barrier.
__global__ __launch_bounds__(256, 2)
void attn_fwd_bf16(const short* __restrict__ Qb, const short* __restrict__ Kb,
                   const short* __restrict__ Vt, float* __restrict__ Out)
{
    const int bh   = blockIdx.x;           // 0..63 (fast dim)
    const int qt   = NQT - 1 - blockIdx.y; // heavy q-tiles dispatch first
    const int tid  = threadIdx.x;
    const int wid  = tid >> 6;             // 0..3
    const int lane = tid & 63;
    const int lq32 = lane & 31;
    const int hi   = lane >> 5;

    const int nkv = 2 * qt + 2;            // 64-wide kv tiles (always even)

    const short* Qp  = Qb + (size_t)bh * S_LEN * D_DIM;
    const short* Kp  = Kb + (size_t)bh * S_LEN * D_DIM;
    const short* Vtp = Vt + (size_t)bh * D_DIM * S_LEN;
    float*       Op  = Out + (size_t)bh * S_LEN * D_DIM;

    __shared__ __align__(16) short Kl[3][64 * 64];   // 3-slot K ring
    __shared__ __align__(16) short Vl[3][64 * 64];   // 3-slot V^T ring (permuted)

    const int q0   = qt * 128 + wid * 32;
    const int Tmax = (q0 + 31) >> 6;       // last kv tile this wave needs

    bf16x8 qf[4];
    #pragma unroll
    for (int c = 0; c < 4; ++c)
        qf[c] = *(const bf16x8*)(Qp + (size_t)(q0 + lq32) * D_DIM + c * 16 + hi * 8);

    f32x16 acc0 = (f32x16)0.f, acc1 = (f32x16)0.f;
    float m = -1e30f, l = 0.f;

    s16x4 kreg[4], vreg[4];
    f32x16 sA0, sA1, sB0, sB1;

    // ---- prologue: tile 0 staged + QK'd ----
    ISSUE_B(0);
    WRITE_LDS_B(&Kl[0][0], &Vl[0][0]);
    __syncthreads();
    ISSUE_B(1);
    QK32(sA0, sA1, 0, &Kl[0][0]);          // tile 0 always needed (kv0=0 <= q0+31)

    for (int t = 0; t < nkv; t += 2) {
        // ---- step A: stage t+1, QK(t+1) || SMPV(t) ----
        {
            const int b1 = (t + 1) % 3;
            WRITE_LDS_B(&Kl[b1][0], &Vl[b1][0]);
            if (t + 2 < nkv) ISSUE_B(t + 2);
            __syncthreads();
            if (t + 1 <= Tmax) QK32(sB0, sB1, 64 * (t + 1), &Kl[b1][0]);
            if (t     <= Tmax) SMPV32(sA0, sA1, (&Vl[t % 3][0]));
        }
        // ---- step B: stage t+2, QK(t+2) || SMPV(t+1) ----
        if (t + 2 < nkv) {
            const int b2 = (t + 2) % 3;
            WRITE_LDS_B(&Kl[b2][0], &Vl[b2][0]);
            if (t + 3 < nkv) ISSUE_B(t + 3);
            __syncthreads();
            if (t + 2 <= Tmax) QK32(sA0, sA1, 64 * (t + 2), &Kl[b2][0]);
        }
        if (t + 1 <= Tmax) SMPV32(sB0, sB1, (&Vl[(t + 1) % 3][0]));
    }

    // ---- epilogue: combine half-sums, O = acc / l ----
    l = xhalf_sum(l);
    const float il = 1.f / l;
    #pragma unroll
    for (int r = 0; r < 16; ++r) {
        const int qr   = (r & 3) + 8 * (r >> 2) + 4 * hi;
        const float vl = __shfl(il, qr);
        Op[(size_t)(q0 + qr) * D_DIM + lq32]      = acc0[r] * vl;
        Op[(size_t)(q0 + qr) * D_DIM + 32 + lq32] = acc1[r] * vl;
    }
}

extern "C" void kernel_launch(void* const* d_in, const int* in_sizes, int n_in,
                              void* d_out, int out_size, void* d_ws, size_t ws_size,
                              hipStream_t stream) {
    const float* q = (const float*)d_in[0];
    const float* k = (const float*)d_in[1];
    const float* v = (const float*)d_in[2];
    // d_in[3] (causal tril mask) handled analytically.
    float* out = (float*)d_out;
    (void)in_sizes; (void)n_in; (void)out_size; (void)ws_size;

    // ws: Qb, Kb, Vt bf16 tensors (50.3 MB; harness ws verified >= this in R6)
    short* Qb = (short*)d_ws;
    short* Kb = Qb + TEN_ELEMS;
    short* Vt = Kb + TEN_ELEMS;
    cvt_qk_kernel<<<TEN_ELEMS / 8 / 256, 256, 0, stream>>>(q, k, Qb, Kb);
    vt_kernel<<<dim3(S_LEN / 64, BH), 256, 0, stream>>>(v, Vt);
    attn_fwd_bf16<<<dim3(BH, NQT), 256, 0, stream>>>(Qb, Kb, Vt, out);
}

// Round 14
// 89.267 us; speedup vs baseline: 1.1148x; 1.0735x over previous
//
#include <hip/hip_runtime.h>
#include <hip/hip_bf16.h>
#include <stdint.h>

#define S_LEN 2048
#define D_DIM 64
#define BH    64
#define NQT   16          // q-tiles of 128 rows
#define LOG2E 1.44269504088896f
#define THR   8.0f
#define TEN_ELEMS (BH * S_LEN * D_DIM)

typedef __attribute__((ext_vector_type(8)))  short bf16x8;
typedef __attribute__((ext_vector_type(4)))  short s16x4;
typedef __attribute__((ext_vector_type(4)))  float f32x4;
typedef __attribute__((ext_vector_type(16))) float f32x16;
typedef __attribute__((ext_vector_type(4)))  uint32_t u32x4;

__device__ __forceinline__ short f2bf(float f) {
    uint32_t u = __builtin_bit_cast(uint32_t, f);
    u += 0x7FFFu + ((u >> 16) & 1u);   // RNE
    return (short)(u >> 16);
}

// packed f32->bf16 (emits v_cvt_pk_bf16_f32); memcpy because __hip_bfloat162
// is not trivially copyable.
__device__ __forceinline__ uint32_t pkbf(float lo, float hi) {
    __hip_bfloat162 h = __float22bfloat162_rn(make_float2(lo, hi));
    uint32_t r;
    __builtin_memcpy(&r, &h, 4);
    return r;
}

__device__ __forceinline__ float xhalf_max(float v) {
    return fmaxf(v, __shfl_xor(v, 32));
}
__device__ __forceinline__ float xhalf_sum(float v) {
    return v + __shfl_xor(v, 32);
}

// XOR swizzle on short-index of a [rows][64]-short tile (byte bits 4..6).
__device__ __forceinline__ int swz(int row, int col) {
    return (row * 64 + col) ^ ((row & 7) << 3);
}

#if __has_builtin(__builtin_amdgcn_exp2f)
#define EXP2(x) __builtin_amdgcn_exp2f(x)
#else
#define EXP2(x) exp2f(x)
#endif

// async global->LDS, 16B per lane; LDS dest = wave-uniform base + lane*16.
typedef __attribute__((address_space(1))) const uint32_t glb_u32;
typedef __attribute__((address_space(3))) uint32_t lds_u32;
__device__ __forceinline__ void llds16(const short* g, short* l) {
    __builtin_amdgcn_global_load_lds((glb_u32*)g, (lds_u32*)l, 16, 0, 0);
}

// ============================ pre-pass kernels ============================
// ws layout (shorts):
//   Qb   [0, 8.4M)      scaled bf16, linear [bh][s][d]
//   Kimg [8.4M, 16.8M)  per-64x64-tile LDS images, XOR-swizzled
//   Vimg [16.8M, 25.2M) per-tile images: transposed + quad-permuted + swizzled
__global__ __launch_bounds__(256)
void cvt_qk_kernel(const float* __restrict__ Q, const float* __restrict__ K,
                   short* __restrict__ Qb, short* __restrict__ Kimg)
{
    const size_t gid = (size_t)blockIdx.x * 256 + threadIdx.x;
    const size_t off = gid * 8;
    const float sc = 0.125f * LOG2E;
    f32x4 a0 = *(const f32x4*)(Q + off), a1 = *(const f32x4*)(Q + off + 4);
    f32x4 b0 = *(const f32x4*)(K + off), b1 = *(const f32x4*)(K + off + 4);
    bf16x8 qa, kb;
    #pragma unroll
    for (int j = 0; j < 4; ++j) {
        qa[j] = f2bf(a0[j] * sc); qa[4 + j] = f2bf(a1[j] * sc);
        kb[j] = f2bf(b0[j]);      kb[4 + j] = f2bf(b1[j]);
    }
    *(bf16x8*)(Qb + off) = qa;
    // K tile image: row = s&63, kt-linear base = (s>>6)*4096; 8-short block
    // at swz(row, d0) stays a contiguous aligned 16B block (swz flips bits 3..5).
    const size_t s  = off >> 6;
    const int    d0 = (int)(off & 63);
    const int    row = (int)(s & 63);
    *(bf16x8*)(Kimg + (s >> 6) * 4096 + swz(row, d0)) = kb;
}

// V image: value V[kv][d] stored at swz(d, sigma(kv)); sigma = quad 1<->2
// within each 16-kv group, so the hot kernel's PV A-fragment is a straight
// pack of each lane's own P values (validated R11).
__global__ __launch_bounds__(256)
void vt_kernel(const float* __restrict__ V, short* __restrict__ Vimg)
{
    const int kt = blockIdx.x;              // kv tile 0..31
    const int bh = blockIdx.y;
    const float* Vp = V + (size_t)bh * S_LEN * D_DIM + (size_t)kt * 64 * D_DIM;
    short* Vo = Vimg + ((size_t)bh * 32 + kt) * 4096;
    __shared__ short T[64][72];             // +8 pad
    const int tid = threadIdx.x;
    const int row = tid >> 2, q4 = tid & 3;
    #pragma unroll
    for (int j = 0; j < 4; ++j) {
        f32x4 v = *(const f32x4*)(Vp + row * D_DIM + q4 * 16 + j * 4);
        #pragma unroll
        for (int e = 0; e < 4; ++e) T[row][q4 * 16 + j * 4 + e] = f2bf(v[e]);
    }
    __syncthreads();
    const int d = tid >> 2, kq = tid & 3;
    #pragma unroll
    for (int j = 0; j < 4; ++j) {
        s16x4 w;
        #pragma unroll
        for (int e = 0; e < 4; ++e) w[e] = T[kq * 16 + j * 4 + e][d];
        const int jd = (j == 1) ? 2 : ((j == 2) ? 1 : j);   // quad 1 <-> 2
        *(s16x4*)&Vo[swz(d, kq * 16 + jd * 4)] = w;
    }
}

// ============================ hot kernel ============================
// staging = pure linear 8KB image copy per tensor: 2 global_load_lds
// dwordx4 issues per wave per tensor (wave w covers shorts [w*1024, w*1024+1024)).
#define STAGE(kb, buf) do { \
    const short* ks_ = Kimg + ((size_t)bh * 32 + (kb)) * 4096; \
    const short* vs_ = Vimg + ((size_t)bh * 32 + (kb)) * 4096; \
    const int wo_ = wid * 1024; \
    llds16(ks_ + wo_ + lane * 8,       &Kl[buf][wo_]); \
    llds16(ks_ + wo_ + 512 + lane * 8, &Kl[buf][wo_ + 512]); \
    llds16(vs_ + wo_ + lane * 8,       &Vl[buf][wo_]); \
    llds16(vs_ + wo_ + 512 + lane * 8, &Vl[buf][wo_ + 512]); \
} while (0)

// PV A-fragment: straight pack of the lane's 8 P-values (V rows pre-permuted).
#define MKFRAG(dst, sv, R0) do { \
    u32x4 t_; \
    t_[0] = pkbf(sv[(R0)+0], sv[(R0)+1]); \
    t_[1] = pkbf(sv[(R0)+2], sv[(R0)+3]); \
    t_[2] = pkbf(sv[(R0)+4], sv[(R0)+5]); \
    t_[3] = pkbf(sv[(R0)+6], sv[(R0)+7]); \
    dst = __builtin_bit_cast(bf16x8, t_); \
} while (0)

#define PVSTEP(pa, koff, acc0, acc1, b) do { \
    bf16x8 vf0_ = *(const bf16x8*)&Vl[b][swz(lq32,      (koff) + hi * 8)]; \
    bf16x8 vf1_ = *(const bf16x8*)&Vl[b][swz(32 + lq32, (koff) + hi * 8)]; \
    acc0 = __builtin_amdgcn_mfma_f32_32x32x16_bf16(pa, vf0_, acc0, 0, 0, 0); \
    acc1 = __builtin_amdgcn_mfma_f32_32x32x16_bf16(pa, vf1_, acc1, 0, 0, 0); \
} while (0)

// Swapped QK^T with 32x32x16: S^T[kv][q]; lane: q = lq32,
// kv = kvsub*32 + (r&3) + 8*(r>>2) + 4*hi.  Softmax fully in-lane + 1 xhalf.
#define COMPUTE32(qf, acc0, acc1, mm, ll, q0, kv0, b) do { \
    f32x16 s0_ = (f32x16)0.f, s1_ = (f32x16)0.f; \
    __builtin_amdgcn_s_setprio(1); \
    _Pragma("unroll") for (int c = 0; c < 4; ++c) { \
        bf16x8 k0_ = *(const bf16x8*)&Kl[b][swz(lq32,      c * 16 + hi * 8)]; \
        bf16x8 k1_ = *(const bf16x8*)&Kl[b][swz(32 + lq32, c * 16 + hi * 8)]; \
        s0_ = __builtin_amdgcn_mfma_f32_32x32x16_bf16(k0_, qf[c], s0_, 0, 0, 0); \
        s1_ = __builtin_amdgcn_mfma_f32_32x32x16_bf16(k1_, qf[c], s1_, 0, 0, 0); \
    } \
    __builtin_amdgcn_s_setprio(0); \
    if ((kv0) + 63 > (q0)) {   /* diagonal tile: causal mask */ \
        _Pragma("unroll") for (int r = 0; r < 16; ++r) { \
            const int kvr_ = (r & 3) + 8 * (r >> 2) + 4 * hi; \
            if ((kv0) + kvr_      > (q0) + lq32) s0_[r] = -1e30f; \
            if ((kv0) + 32 + kvr_ > (q0) + lq32) s1_[r] = -1e30f; \
        } \
    } \
    float m0_ = fmaxf(s0_[0], s1_[0]), m1_ = fmaxf(s0_[1], s1_[1]); \
    float m2_ = fmaxf(s0_[2], s1_[2]), m3_ = fmaxf(s0_[3], s1_[3]); \
    _Pragma("unroll") for (int r = 4; r < 16; r += 4) { \
        m0_ = fmaxf(m0_, fmaxf(s0_[r],     s1_[r])); \
        m1_ = fmaxf(m1_, fmaxf(s0_[r + 1], s1_[r + 1])); \
        m2_ = fmaxf(m2_, fmaxf(s0_[r + 2], s1_[r + 2])); \
        m3_ = fmaxf(m3_, fmaxf(s0_[r + 3], s1_[r + 3])); \
    } \
    float pmax_ = xhalf_max(fmaxf(fmaxf(m0_, m1_), fmaxf(m2_, m3_))); \
    if (!__all(pmax_ <= (mm) + THR)) {      /* defer-max: rare rescale */ \
        const float mn_ = fmaxf((mm), pmax_); \
        const float f_  = EXP2((mm) - mn_); \
        (ll) *= f_; \
        _Pragma("unroll") for (int r = 0; r < 16; ++r) { \
            const float fr_ = __shfl(f_, (r & 3) + 8 * (r >> 2) + 4 * hi); \
            acc0[r] *= fr_; acc1[r] *= fr_; \
        } \
        (mm) = mn_; \
    } \
    float t0_ = 0.f, t1_ = 0.f, t2_ = 0.f, t3_ = 0.f; \
    _Pragma("unroll") for (int r = 0; r < 16; r += 4) { \
        s0_[r]     = EXP2(s0_[r]     - (mm)); s1_[r]     = EXP2(s1_[r]     - (mm)); \
        s0_[r + 1] = EXP2(s0_[r + 1] - (mm)); s1_[r + 1] = EXP2(s1_[r + 1] - (mm)); \
        s0_[r + 2] = EXP2(s0_[r + 2] - (mm)); s1_[r + 2] = EXP2(s1_[r + 2] - (mm)); \
        s0_[r + 3] = EXP2(s0_[r + 3] - (mm)); s1_[r + 3] = EXP2(s1_[r + 3] - (mm)); \
        t0_ += s0_[r]     + s1_[r]; \
        t1_ += s0_[r + 1] + s1_[r + 1]; \
        t2_ += s0_[r + 2] + s1_[r + 2]; \
        t3_ += s0_[r + 3] + s1_[r + 3]; \
    } \
    (ll) += (t0_ + t1_) + (t2_ + t3_);      /* in-lane half-sum; combine at end */ \
    bf16x8 pa0_, pa1_, pa2_, pa3_; \
    MKFRAG(pa0_, s0_, 0); MKFRAG(pa1_, s0_, 8); \
    MKFRAG(pa2_, s1_, 0); MKFRAG(pa3_, s1_, 8); \
    __builtin_amdgcn_s_setprio(1); \
    PVSTEP(pa0_, 0,  acc0, acc1, b); \
    PVSTEP(pa1_, 16, acc0, acc1, b); \
    PVSTEP(pa2_, 32, acc0, acc1, b); \
    PVSTEP(pa3_, 48, acc0, acc1, b); \
    __builtin_amdgcn_s_setprio(0); \
} while (0)

// One 128-row q-tile per block, grid 64x16 = 1024 blocks, heavy-first
// (R11 geometry — R12's 8-wave blocks and R13's manual pipeline both
// regressed; the scheduler's cross-wave overlap already covers it).
__global__ __launch_bounds__(256, 2)
void attn_fwd_bf16(const short* __restrict__ Qb, const short* __restrict__ Kimg,
                   const short* __restrict__ Vimg, float* __restrict__ Out)
{
    const int bh   = blockIdx.x;           // 0..63 (fast dim)
    const int qt   = NQT - 1 - blockIdx.y; // heavy q-tiles dispatch first
    const int tid  = threadIdx.x;
    const int wid  = tid >> 6;             // 0..3
    const int lane = tid & 63;
    const int lq32 = lane & 31;
    const int hi   = lane >> 5;

    const int nkv = 2 * qt + 2;            // 64-wide kv tiles

    const short* Qp = Qb + (size_t)bh * S_LEN * D_DIM;
    float*       Op = Out + (size_t)bh * S_LEN * D_DIM;

    __shared__ __align__(16) short Kl[2][64 * 64];
    __shared__ __align__(16) short Vl[2][64 * 64];

    const int q0 = qt * 128 + wid * 32;

    // Q fragments (B-operand): col q = lq32, k(d) = c*16 + hi*8 + j
    bf16x8 qf[4];
    #pragma unroll
    for (int c = 0; c < 4; ++c)
        qf[c] = *(const bf16x8*)(Qp + (size_t)(q0 + lq32) * D_DIM + c * 16 + hi * 8);

    f32x16 acc0 = (f32x16)0.f, acc1 = (f32x16)0.f;
    float m = -1e30f, l = 0.f;

    STAGE(0, 0);
    __syncthreads();                        // vmcnt drained: tile 0 resident

    for (int j = 0; j < nkv; ++j) {
        const int  buf  = j & 1;
        const bool more = (j + 1) < nkv;
        if (more) STAGE(j + 1, buf ^ 1);    // DMA flies under compute
        if (j * 64 <= q0 + 31) COMPUTE32(qf, acc0, acc1, m, l, q0, j * 64, buf);
        if (more) __syncthreads();          // drains DMA; frees buf for j+2
    }

    // ---- epilogue: combine half-sums, O = acc / l ----
    l = xhalf_sum(l);
    const float il = 1.f / l;
    #pragma unroll
    for (int r = 0; r < 16; ++r) {
        const int qr   = (r & 3) + 8 * (r >> 2) + 4 * hi;
        const float vl = __shfl(il, qr);
        Op[(size_t)(q0 + qr) * D_DIM + lq32]      = acc0[r] * vl;
        Op[(size_t)(q0 + qr) * D_DIM + 32 + lq32] = acc1[r] * vl;
    }
}

extern "C" void kernel_launch(void* const* d_in, const int* in_sizes, int n_in,
                              void* d_out, int out_size, void* d_ws, size_t ws_size,
                              hipStream_t stream) {
    const float* q = (const float*)d_in[0];
    const float* k = (const float*)d_in[1];
    const float* v = (const float*)d_in[2];
    // d_in[3] (causal tril mask) handled analytically.
    float* out = (float*)d_out;
    (void)in_sizes; (void)n_in; (void)out_size; (void)ws_size;

    // ws: Qb linear + Kimg/Vimg per-tile LDS images (50.3 MB total)
    short* Qb   = (short*)d_ws;
    short* Kimg = Qb + TEN_ELEMS;
    short* Vimg = Kimg + TEN_ELEMS;
    cvt_qk_kernel<<<TEN_ELEMS / 8 / 256, 256, 0, stream>>>(q, k, Qb, Kimg);
    vt_kernel<<<dim3(S_LEN / 64, BH), 256, 0, stream>>>(v, Vimg);
    attn_fwd_bf16<<<dim3(BH, NQT), 256, 0, stream>>>(Qb, Kimg, Vimg, out);
}